// Round 3
// baseline (356.781 us; speedup 1.0000x reference)
//
#include <hip/hip_runtime.h>

#define N_SAMP   1024
#define IN_F     512
#define OUT_F    512
#define N_HEADS  32
#define N_SPLITS 4
#define DELTA_SCALE 0.1f

// ---- vector helpers (float2 for base path, float4 for delta path) ----
template <int CPT> struct VecT;
template <> struct VecT<2> { using type = float2; };
template <> struct VecT<4> { using type = float4; };

__device__ __forceinline__ void vzero(float2& v) { v.x = 0.f; v.y = 0.f; }
__device__ __forceinline__ void vzero(float4& v) { v.x = v.y = v.z = v.w = 0.f; }
__device__ __forceinline__ void vfma(float2& a, float x, const float2& w) {
    a.x += x * w.x; a.y += x * w.y;
}
__device__ __forceinline__ void vfma(float4& a, float x, const float4& w) {
    a.x += x * w.x; a.y += x * w.y; a.z += x * w.z; a.w += x * w.w;
}
__device__ __forceinline__ void vatomic(float* p, const float2& a, float s) {
    atomicAdd(p + 0, s * a.x); atomicAdd(p + 1, s * a.y);
}
__device__ __forceinline__ void vatomic(float* p, const float4& a, float s) {
    atomicAdd(p + 0, s * a.x); atomicAdd(p + 1, s * a.y);
    atomicAdd(p + 2, s * a.z); atomicAdd(p + 3, s * a.w);
}

// ---- init: out[n][c] = bias[head_ix[n]][c]  (atomic passes then accumulate) ----
__global__ __launch_bounds__(256) void init_kernel(
    const int* __restrict__ head_ix, const float* __restrict__ bias,
    float* __restrict__ out)
{
    const int idx = blockIdx.x * 256 + threadIdx.x;   // one float4 per thread
    const int n   = idx >> 7;                         // 128 quads per sample row
    const int cq  = idx & 127;
    const int h   = head_ix[n];
    const float4 b = *(const float4*)(bias + (size_t)h * OUT_F + cq * 4);
    *(float4*)(out + (size_t)n * OUT_F + cq * 4) = b;
}

// ---- grouped streaming pass over one (group, k-slice) weight tile ----
// Thread owns CPT fixed output columns; rows iterate -> every wave-load is
// 64 lanes x CPT*4 B of CONTIGUOUS unique bytes. 8-deep register ring with
// NO rotation copies (slot = iter & 7, filled 7 iterations ahead) keeps 7
// loads in flight per thread (the R2 kernel drained vmcnt(0) every 4 loads).
// X rows staged TRANSPOSED in LDS (Xs[k][s]) -> wave-uniform ds_read_b128
// broadcast. Results scattered with fire-and-forget f32 atomics.
template <int J, int KR, int CPT, bool SPLIT>
__device__ __forceinline__ void group_pass(
    const float* __restrict__ X, const int* __restrict__ head_ix,
    const int* __restrict__ split_ix, const float* __restrict__ Wg,
    float* __restrict__ out, int g, int kb, float scale,
    int* list, int* cntp, float* Xs /* [KR][J] */)
{
    constexpr int RPI = CPT / 2;        // weight rows consumed per iteration
    constexpr int NIT = KR / RPI;       // = 64 for both configs
    constexpr int CT  = OUT_F / CPT;    // threads spanning one row
    constexpr int Q   = KR / 4;         // float4 chunks per staged x row
    using V = typename VecT<CPT>::type;

    const int tid = threadIdx.x;

    if (tid == 0) *cntp = 0;
    __syncthreads();
    {   // build the sample list for group g (one int4 of each index array/thread)
        const int4 h4 = ((const int4*)head_ix)[tid];
        int4 s4 = make_int4(0, 0, 0, 0);
        if (SPLIT) s4 = ((const int4*)split_ix)[tid];
        const int hh[4] = {h4.x, h4.y, h4.z, h4.w};
        const int ss[4] = {s4.x, s4.y, s4.z, s4.w};
#pragma unroll
        for (int j = 0; j < 4; ++j) {
            const bool hit = SPLIT ? (hh[j] * N_SPLITS + ss[j] == g) : (hh[j] == g);
            if (hit) { int p = atomicAdd(cntp, 1); list[p] = tid * 4 + j; }
        }
    }
    __syncthreads();
    const int total = *cntp;
    if (total == 0) return;

    const int r = tid / CT;             // row offset within an iteration (0 or 0/1)
    const int c = (tid % CT) * CPT;     // owned columns

    for (int s0 = 0; s0 < total; s0 += J) {
        const int nc = min(total - s0, J);

        // stage Xs[KR][J] transposed, zero-padded past nc
        for (int i = tid; i < J * Q; i += 256) {
            const int s = i / Q, q4 = i % Q;
            float4 v = make_float4(0.f, 0.f, 0.f, 0.f);
            if (s < nc)
                v = *(const float4*)(X + (size_t)list[s0 + s] * IN_F + kb + q4 * 4);
            Xs[(q4 * 4 + 0) * J + s] = v.x;
            Xs[(q4 * 4 + 1) * J + s] = v.y;
            Xs[(q4 * 4 + 2) * J + s] = v.z;
            Xs[(q4 * 4 + 3) * J + s] = v.w;
        }
        __syncthreads();

        V acc[J];
#pragma unroll
        for (int s = 0; s < J; ++s) vzero(acc[s]);

        const float* wp = Wg + ((size_t)kb + r) * OUT_F + c;

        V ring[8];
#pragma unroll
        for (int p = 0; p < 7; ++p)
            ring[p] = *(const V*)(wp + (size_t)p * RPI * OUT_F);

        for (int i = 0; i < NIT; i += 8) {
#pragma unroll
            for (int u = 0; u < 8; ++u) {
                int nx = i + u + 7;                 // fill 7 ahead (clamped tail)
                if (nx > NIT - 1) nx = NIT - 1;
                ring[(u + 7) & 7] = *(const V*)(wp + (size_t)nx * RPI * OUT_F);

                const V w = ring[u];                // waits with 7 loads outstanding
                const float* xrow = Xs + (size_t)((i + u) * RPI + r) * J;
#pragma unroll
                for (int s4 = 0; s4 < J / 4; ++s4) {
                    const float4 xv = *(const float4*)(xrow + s4 * 4); // broadcast
                    vfma(acc[s4 * 4 + 0], xv.x, w);
                    vfma(acc[s4 * 4 + 1], xv.y, w);
                    vfma(acc[s4 * 4 + 2], xv.z, w);
                    vfma(acc[s4 * 4 + 3], xv.w, w);
                }
            }
        }

#pragma unroll
        for (int s = 0; s < J; ++s)
            if (s < nc)
                vatomic(out + (size_t)list[s0 + s] * OUT_F + c, acc[s], scale);

        __syncthreads();   // protect Xs before a (rare) next chunk restages
    }
}

// Fused: 256 base blocks (32 heads x 8 k-slices, J=40, float2/thread) +
// 512 delta blocks (128 combos x 4 k-slices, J=16, float4/thread),
// interleaved bid%3 so each CU co-schedules 1 base + 2 delta blocks
// (VALU-heavy + memory-heavy mix).
__global__ __launch_bounds__(256, 3) void lms_main(
    const float* __restrict__ X, const int* __restrict__ head_ix,
    const int* __restrict__ split_ix, const float* __restrict__ W,
    const float* __restrict__ D, float* __restrict__ out)
{
    __shared__ float Xs[64 * 40];       // max(64*40, 128*16) floats
    __shared__ int   list[N_SAMP];
    __shared__ int   cnt;

    const int bid = blockIdx.x;
    if (bid % 3 == 0) {
        const int id = bid / 3;         // 0..255
        const int head = id & 31, ks = id >> 5;
        group_pass<40, 64, 2, false>(X, head_ix, split_ix,
            W + (size_t)head * IN_F * OUT_F, out, head, ks * 64, 1.0f,
            list, &cnt, Xs);
    } else {
        const int id = (bid / 3) * 2 + (bid % 3) - 1;  // 0..511
        const int combo = id & 127, ks = id >> 7;
        group_pass<16, 128, 4, true>(X, head_ix, split_ix,
            D + (size_t)combo * IN_F * OUT_F, out, combo, ks * 128, DELTA_SCALE,
            list, &cnt, Xs);
    }
}

extern "C" void kernel_launch(void* const* d_in, const int* in_sizes, int n_in,
                              void* d_out, int out_size, void* d_ws, size_t ws_size,
                              hipStream_t stream) {
    const float* X        = (const float*)d_in[0];
    const int*   head_ix  = (const int*)d_in[1];
    const int*   split_ix = (const int*)d_in[2];
    const float* W        = (const float*)d_in[3];
    const float* D        = (const float*)d_in[4];
    const float* bias     = (const float*)d_in[5];
    float*       out      = (float*)d_out;

    init_kernel<<<(N_SAMP * OUT_F / 4) / 256, 256, 0, stream>>>(head_ix, bias, out);
    lms_main<<<768, 256, 0, stream>>>(X, head_ix, split_ix, W, D, out);
}

// Round 4
// 270.843 us; speedup vs baseline: 1.3173x; 1.3173x over previous
//
#include <hip/hip_runtime.h>

#define N_SAMP   1024
#define IN_F     512
#define OUT_F    512
#define N_HEADS  32
#define N_SPLITS 4
#define DELTA_SCALE 0.1f

// 16-byte global->LDS DMA (wave-uniform LDS base + lane*16; guide §5:
// compiler never auto-emits this, and width=16 alone was a 1.7x step in the
// m93->m97 GEMM ladder).
__device__ __forceinline__ void lds_dma16(const float* g, float* l) {
    __builtin_amdgcn_global_load_lds(
        (const __attribute__((address_space(1))) void*)g,
        (__attribute__((address_space(3))) void*)l, 16, 0, 0);
}

// Grouped pass, m97-style K-loop. Block = (group g, 64-col tile).
//  - weight chunk (KB=64 rows x 64 cols, 16 KB) streamed to LDS via
//    global_load_lds; X chunk (J x 64, zero-filled tail) staged beside it.
//  - thread (r = slot-group 0..7, c = col-pair 0..31) owns slots r*Jr..r*Jr+Jr-1
//    for ALL k -> exact sole-writer epilogue: NO atomics (R3's 244 MB
//    WRITE_SIZE atomic wall), no k-split reduction.
//  - DELTA=false: g = head, out = acc + bias (covers every output; no init)
//    DELTA=true : g = head*4+split, out += 0.1*acc (plain RMW, stream-ordered)
template <int J, bool DELTA>
__global__ __launch_bounds__(256) void lms_pass(
    const float* __restrict__ X, const int* __restrict__ head_ix,
    const int* __restrict__ split_ix, const float* __restrict__ Wt,
    const float* __restrict__ bias, float* __restrict__ out)
{
    constexpr int TILE = 64;            // columns per block
    constexpr int KB   = 64;            // k rows per chunk
    constexpr int CT   = 32;            // threads spanning a row (TILE/2)
    constexpr int R    = 8;             // slot groups
    constexpr int Jr   = J / R;         // slots per thread
    constexpr int XW   = KB + 4;        // padded Xb row (bank spread, 16B align)
    constexpr int Q    = KB / 4;        // float4 per Xb row
    constexpr int NISS = (KB * TILE * 4) / (256 * 16);  // DMA issues/thread = 4

    __shared__ float Wb[KB * TILE];     // 16 KB, layout = linear global order
    __shared__ float Xb[J * XW];
    __shared__ int   list[N_SAMP];
    __shared__ int   cnt;

    const int g   = blockIdx.y;
    const int c0  = blockIdx.x * TILE;
    const int tid = threadIdx.x;

    if (tid == 0) cnt = 0;
    __syncthreads();
    for (int i = tid; i < N_SAMP; i += 256) {
        const int key = DELTA ? head_ix[i] * N_SPLITS + split_ix[i] : head_ix[i];
        if (key == g) { int p = atomicAdd(&cnt, 1); list[p] = i; }
    }
    __syncthreads();
    const int total = cnt;
    if (total == 0) return;

    const float* Wg = Wt + (size_t)g * (IN_F * OUT_F) + c0;

    const int c    = tid & 31;          // col pair 0..31
    const int r    = tid >> 5;          // slot group 0..7
    const int wave = tid >> 6, lane = tid & 63;

    float2 bv;
    if (!DELTA) bv = *(const float2*)(bias + (size_t)g * OUT_F + c0 + c * 2);

    for (int s0 = 0; s0 < total; s0 += J) {     // expected 1 iteration
        const int nc = min(total - s0, J);

        float2 acc[Jr];
#pragma unroll
        for (int j = 0; j < Jr; ++j) { acc[j].x = 0.f; acc[j].y = 0.f; }

        for (int k0 = 0; k0 < IN_F; k0 += KB) {
            __syncthreads();    // prior chunk fully consumed before restage

            // X chunk: Xb[s][0..63], zero-filled past nc
            for (int i = tid; i < J * Q; i += 256) {
                const int s = i / Q, q = i - s * Q;
                float4 v = make_float4(0.f, 0.f, 0.f, 0.f);
                if (s < nc)
                    v = *(const float4*)(X + (size_t)list[s0 + s] * IN_F + k0 + q * 4);
                *(float4*)(&Xb[s * XW + q * 4]) = v;
            }

            // W chunk DMA: 16 segments of 1 KB (4 rows x 256 B), one per
            // (wave, iter); lane's global addr strides rows of W.
            const float* wk = Wg + (size_t)k0 * OUT_F;
#pragma unroll
            for (int it = 0; it < NISS; ++it) {
                const int seg  = it * 4 + wave;
                const int unit = seg * 64 + lane;        // 16B unit index
                const int row  = unit >> 4;              // /16 units per row
                const int col  = unit & 15;
                lds_dma16(wk + (size_t)row * OUT_F + col * 4, &Wb[seg * 256]);
            }
            __syncthreads();    // compiler drains vmcnt(0) here (DMA landed)

            // consume: per 4 k-rows, Jr broadcast x-b128 reads + 4 w-b64 reads
            for (int k4 = 0; k4 < KB; k4 += 4) {
                const float2 w0 = *(const float2*)(&Wb[(k4 + 0) * TILE + c * 2]);
                const float2 w1 = *(const float2*)(&Wb[(k4 + 1) * TILE + c * 2]);
                const float2 w2 = *(const float2*)(&Wb[(k4 + 2) * TILE + c * 2]);
                const float2 w3 = *(const float2*)(&Wb[(k4 + 3) * TILE + c * 2]);
#pragma unroll
                for (int j = 0; j < Jr; ++j) {
                    const float4 xv = *(const float4*)(&Xb[(r * Jr + j) * XW + k4]);
                    acc[j].x += xv.x * w0.x; acc[j].y += xv.x * w0.y;
                    acc[j].x += xv.y * w1.x; acc[j].y += xv.y * w1.y;
                    acc[j].x += xv.z * w2.x; acc[j].y += xv.z * w2.y;
                    acc[j].x += xv.w * w3.x; acc[j].y += xv.w * w3.y;
                }
            }
        }

        // epilogue: sole writer per (sample, col-pair)
#pragma unroll
        for (int j = 0; j < Jr; ++j) {
            const int s = r * Jr + j;
            if (s < nc) {
                float* op = out + (size_t)list[s0 + s] * OUT_F + c0 + c * 2;
                float2 res;
                if (DELTA) {
                    const float2 cur = *(const float2*)op;
                    res.x = cur.x + DELTA_SCALE * acc[j].x;
                    res.y = cur.y + DELTA_SCALE * acc[j].y;
                } else {
                    res.x = acc[j].x + bv.x;
                    res.y = acc[j].y + bv.y;
                }
                *(float2*)op = res;
            }
        }
    }
}

extern "C" void kernel_launch(void* const* d_in, const int* in_sizes, int n_in,
                              void* d_out, int out_size, void* d_ws, size_t ws_size,
                              hipStream_t stream) {
    const float* X        = (const float*)d_in[0];
    const int*   head_ix  = (const int*)d_in[1];
    const int*   split_ix = (const int*)d_in[2];
    const float* W        = (const float*)d_in[3];
    const float* D        = (const float*)d_in[4];
    const float* bias     = (const float*)d_in[5];
    float*       out      = (float*)d_out;

    // Base: 32 heads x 8 tiles = 256 blocks (1/CU). J=64 covers max head
    // count (~56 = 4.3 sigma) in one slot-chunk; writes acc+bias for every
    // output -> no init kernel.
    dim3 gb(OUT_F / 64, N_HEADS);
    lms_pass<64, false><<<gb, 256, 0, stream>>>(X, head_ix, split_ix, W, bias, out);

    // Delta: 128 combos x 8 tiles = 1024 blocks (4/CU: stage/compute stagger
    // + ~25 KB LDS/block so all 4 fit). J=16 covers mean-8 combos; chunk loop
    // handles stragglers. Stream-ordered RMW after base.
    dim3 gd(OUT_F / 64, N_HEADS * N_SPLITS);
    lms_pass<16, true><<<gd, 256, 0, stream>>>(X, head_ix, split_ix, D, bias, out);
}

// Round 6
// 258.888 us; speedup vs baseline: 1.3781x; 1.0462x over previous
//
#include <hip/hip_runtime.h>

#define N_SAMP   1024
#define IN_F     512
#define OUT_F    512
#define N_HEADS  32
#define N_SPLITS 4
#define DELTA_SCALE 0.1f

// Register-streaming grouped pass with in-block k-split.
//   block = (group g, 64-col tile, slot-group sg)
//   thread = (c2 = col-pair 0..31, kq = k-eighth 0..7)
// W goes HBM -> registers directly (single-use data; LDS staging only added
// barrier drains + 8x ds amplification in R4). Distance-1 double-buffered
// 4-row batches with alternating indices (no register rotation -- R2's
// vmcnt(0) trap). X rows staged once per slot-chunk in LDS, consumed as
// wave-uniform broadcast ds_read_b128. k-partials reduced through one LDS
// round-trip (Red aliases Xs), then a sole-owner epilogue (no atomics --
// R3's 244 MB WRITE_SIZE wall).
//
// R5 bug fixed here: `list` is now built with DETERMINISTIC order-preserving
// compaction (__ballot + popcount prefix + wave-offset scan). R5 used racy
// atomicAdd compaction, so the two sg-blocks of one head disagreed on list
// order and their [0:J) / [J:2J) slices didn't partition the sample set ->
// some samples never written. Every block for group g now derives the same
// index-sorted list.
template <int J, bool DELTA, int NSG, int MINW>
__global__ __launch_bounds__(256, MINW) void lms_stream(
    const float* __restrict__ X, const int* __restrict__ head_ix,
    const int* __restrict__ split_ix, const float* __restrict__ Wt,
    const float* __restrict__ bias, float* __restrict__ out)
{
    constexpr int KQ   = 8;            // k-split ways
    constexpr int KT   = IN_F / KQ;    // 64 k rows per thread
    constexpr int NST  = KT / 4;       // 16 steps of 4 rows
    constexpr int NOUT = (J * 32) / 256;

    __shared__ float buf[J * IN_F];    // Xs[J][512]  <->  Red[KQ][J][32] float2
    __shared__ int   list[N_SAMP];
    __shared__ int   wsum[4];

    const int g    = blockIdx.y / NSG;
    const int sg   = blockIdx.y % NSG;
    const int c0   = blockIdx.x * 64;
    const int tid  = threadIdx.x;
    const int c2   = tid & 31;         // col pair
    const int kq   = tid >> 5;         // k-eighth
    const int lane = tid & 63;
    const int wave = tid >> 6;

    // deterministic order-preserving compaction of samples matching g
    int run = 0;
    for (int r = 0; r < N_SAMP / 256; ++r) {
        const int i   = r * 256 + tid;
        const int key = DELTA ? head_ix[i] * N_SPLITS + split_ix[i] : head_ix[i];
        const bool hit = (key == g);
        const unsigned long long m = __ballot(hit);
        if (lane == 0) wsum[wave] = __popcll(m);
        __syncthreads();
        int base = run;
        for (int w = 0; w < 4; ++w)
            if (w < wave) base += wsum[w];
        if (hit)
            list[base + __popcll(m & ((1ULL << lane) - 1ULL))] = i;
        run += wsum[0] + wsum[1] + wsum[2] + wsum[3];
        __syncthreads();               // wsum consumed before next round
    }
    const int total = run;
    if (total <= sg * J && total > 0) return;   // this sg has no chunk
    if (total == 0) return;

    // thread's W stripe: rows kq*KT .. kq*KT+63, cols c0+2*c2 (+1)
    const float* wp = Wt + (size_t)g * (IN_F * OUT_F)
                    + (size_t)(kq * KT) * OUT_F + c0 + c2 * 2;

    for (int s0 = sg * J; s0 < total; s0 += NSG * J) {
        const int nc = min(total - s0, J);

        __syncthreads();               // buf may still hold previous Red
        for (int i = tid; i < J * (IN_F / 4); i += 256) {
            const int s = i >> 7, q = i & 127;
            float4 v = make_float4(0.f, 0.f, 0.f, 0.f);
            if (s < nc)
                v = *(const float4*)(X + (size_t)list[s0 + s] * IN_F + q * 4);
            *(float4*)(&buf[s * IN_F + q * 4]) = v;
        }
        __syncthreads();

        float2 acc[J];
#pragma unroll
        for (int j = 0; j < J; ++j) { acc[j].x = 0.f; acc[j].y = 0.f; }

        float2 rb[2][4];
#pragma unroll
        for (int u = 0; u < 4; ++u)
            rb[0][u] = *(const float2*)(wp + (size_t)u * OUT_F);

#pragma unroll 2
        for (int st = 0; st < NST; ++st) {
            // prefetch next 4-row batch into the other buffer (clamped tail:
            // redundant L1-hit re-load keeps the body branch-free)
            const int nx = (st + 1 < NST) ? st + 1 : NST - 1;
            const float* wn = wp + (size_t)(nx * 4) * OUT_F;
            const int nb = (st + 1) & 1, cb = st & 1;
#pragma unroll
            for (int u = 0; u < 4; ++u)
                rb[nb][u] = *(const float2*)(wn + (size_t)u * OUT_F);

            const float* xb = &buf[kq * KT + st * 4];
#pragma unroll
            for (int j = 0; j < J; ++j) {
                const float4 xv = *(const float4*)(xb + j * IN_F); // broadcast
                acc[j].x += xv.x * rb[cb][0].x; acc[j].y += xv.x * rb[cb][0].y;
                acc[j].x += xv.y * rb[cb][1].x; acc[j].y += xv.y * rb[cb][1].y;
                acc[j].x += xv.z * rb[cb][2].x; acc[j].y += xv.z * rb[cb][2].y;
                acc[j].x += xv.w * rb[cb][3].x; acc[j].y += xv.w * rb[cb][3].y;
            }
        }

        __syncthreads();               // Xs fully consumed; reuse buf as Red
        float2* Red = (float2*)buf;    // [KQ][J][32]
#pragma unroll
        for (int j = 0; j < J; ++j)
            Red[(kq * J + j) * 32 + c2] = acc[j];
        __syncthreads();

        // sole-owner epilogue: sum the 8 k-partials, write/RMW
#pragma unroll
        for (int t = 0; t < NOUT; ++t) {
            const int oi = t * 256 + tid;
            const int j = oi >> 5, cc = oi & 31;
            if (j < nc) {
                float2 s = make_float2(0.f, 0.f);
#pragma unroll
                for (int q = 0; q < KQ; ++q) {
                    const float2 r = Red[(q * J + j) * 32 + cc];
                    s.x += r.x; s.y += r.y;
                }
                float* op = out + (size_t)list[s0 + j] * OUT_F + c0 + cc * 2;
                float2 res;
                if (DELTA) {
                    const float2 cur = *(const float2*)op;
                    res.x = cur.x + DELTA_SCALE * s.x;
                    res.y = cur.y + DELTA_SCALE * s.y;
                } else {
                    const float2 bv =
                        *(const float2*)(bias + (size_t)g * OUT_F + c0 + cc * 2);
                    res.x = s.x + bv.x;
                    res.y = s.y + bv.y;
                }
                *(float2*)op = res;
            }
        }
    }
}

extern "C" void kernel_launch(void* const* d_in, const int* in_sizes, int n_in,
                              void* d_out, int out_size, void* d_ws, size_t ws_size,
                              hipStream_t stream) {
    const float* X        = (const float*)d_in[0];
    const int*   head_ix  = (const int*)d_in[1];
    const int*   split_ix = (const int*)d_in[2];
    const float* W        = (const float*)d_in[3];
    const float* D        = (const float*)d_in[4];
    const float* bias     = (const float*)d_in[5];
    float*       out      = (float*)d_out;

    // Base: 32 heads x 2 slot-groups x 8 tiles = 512 blocks = 2/CU
    // (LDS ~70 KB/block -> exactly 2 resident). sg-blocks now partition the
    // deterministic list correctly. Writes every output (bias included).
    dim3 gb(OUT_F / 64, N_HEADS * 2);
    lms_stream<32, false, 2, 2><<<gb, 256, 0, stream>>>(
        X, head_ix, split_ix, W, bias, out);

    // Delta: 128 combos x 8 tiles = 1024 blocks = 4/CU (LDS ~37 KB). J=16
    // covers mean-8 combos; chunk loop catches >16 stragglers. RMW after base.
    dim3 gd(OUT_F / 64, N_HEADS * N_SPLITS);
    lms_stream<16, true, 1, 4><<<gd, 256, 0, stream>>>(
        X, head_ix, split_ix, D, bias, out);
}